// Round 10
// baseline (77.048 us; speedup 1.0000x reference)
//
#include <hip/hip_runtime.h>

#define B_N 8192
#define C_N 20000
#define D_N 128
#define CPAD 20096              // 1256 * 16
#define NTILES16 1256           // 16-row center tiles
#define NCHUNK 32               // tiles strided: tile = chunk + 32*j ; grid 32x32 = 4 blocks/CU
#define MARGIN_F 0.15001125f    // 0.15 + (1/40000)*(0.6-0.15)

#define NORM_BLOCKS 2048        // 8192 rows / 4 per block
#define CONV_BLOCKS 2512        // CPAD*128/4/256

typedef __attribute__((ext_vector_type(8))) short bf16x8;
typedef __attribute__((ext_vector_type(4))) float f32x4;

typedef __attribute__((address_space(1))) const unsigned int GUint;
typedef __attribute__((address_space(3))) unsigned int LUint;

__device__ __forceinline__ unsigned short f2bf(float x) {
    union { float f; unsigned int u; } v; v.f = x;
    unsigned int r = v.u + 0x7fffu + ((v.u >> 16) & 1u);
    return (unsigned short)(r >> 16);
}
__device__ __forceinline__ float bf2f(unsigned short h) {
    union { unsigned int u; float f; } v; v.u = ((unsigned int)h) << 16; return v.f;
}

// ---- kernel 1 (fused prep): blocks [0,2048) normalize features; rest convert
// centers -> bf16 (zero-padded to CPAD rows). Per-row corrections to arrays
// (round-3 lesson: contended same-address atomics serialize ~200us).
__global__ __launch_bounds__(256) void k_prep(
    const float* __restrict__ feat, const float* __restrict__ centers,
    const int* __restrict__ labels, unsigned short* __restrict__ fb,
    unsigned short* __restrict__ cb, float* __restrict__ t,
    float* __restrict__ corr_s, unsigned int* __restrict__ corr_c)
{
    const int bid = blockIdx.x;
    if (bid < NORM_BLOCKS) {
        const int lane = threadIdx.x & 63;
        const int row  = bid * 4 + (threadIdx.x >> 6);   // wave per row
        const float2 fv = *(const float2*)(feat + (size_t)row * D_N + lane * 2);
        float ss = fv.x * fv.x + fv.y * fv.y;
        #pragma unroll
        for (int off = 32; off; off >>= 1) ss += __shfl_xor(ss, off);
        const float scale = 1.0f / fmaxf(sqrtf(ss), 1e-12f);
        const float a = fv.x * scale, b = fv.y * scale;
        ushort2 o; o.x = f2bf(a); o.y = f2bf(b);
        *(ushort2*)(fb + (size_t)row * D_N + lane * 2) = o;

        const int lab = labels[row];
        const float2 cv = *(const float2*)(centers + (size_t)lab * D_N + lane * 2);
        float pd = a * cv.x + b * cv.y;                                         // fp32 dot
        float pb = bf2f(o.x) * bf2f(f2bf(cv.x)) + bf2f(o.y) * bf2f(f2bf(cv.y)); // bf16 dot
        #pragma unroll
        for (int off = 32; off; off >>= 1) {
            pd += __shfl_xor(pd, off);
            pb += __shfl_xor(pb, off);
        }
        if (lane == 0) {
            const float tb = MARGIN_F - pd;
            t[row] = tb;
            float cs = fmaxf(tb + pb, 0.0f);                 // label-column term
            unsigned int cc = (tb + pb > 0.0f) ? 1u : 0u;
            if (tb > 0.0f) { cs += 96.0f * tb; cc += 96u; }  // 96 zero-pad columns
            corr_s[row] = cs;
            corr_c[row] = cc;
        }
    } else {
        const int idx = (bid - NORM_BLOCKS) * 256 + threadIdx.x;
        const int e = idx * 4;
        const int row = e >> 7;
        ushort4 o;
        if (row < C_N) {
            const float4 v = *(const float4*)(centers + e);
            o.x = f2bf(v.x); o.y = f2bf(v.y); o.z = f2bf(v.z); o.w = f2bf(v.w);
        } else {
            o.x = 0; o.y = 0; o.z = 0; o.w = 0;
        }
        *(ushort4*)(cb + e) = o;
    }
}

// ---- kernel 2: main. BARRIER-FREE wave-private streaming: each wave owns a
// 2 x 4KB LDS double buffer and its own 16-row center tile stream, paced by
// per-wave counted vmcnt. Zero s_barrier in the loop -> 16 drifting waves/CU
// overlap MFMA/VALU/LDS/stage statistically (R6-R9 lesson: 3 barrier-based
// schedules all pinned at 54us by phase-locked stalls).
__global__ __launch_bounds__(256, 4) void k_main(
    const unsigned short* __restrict__ fb,   // [8192][128] bf16 normalized features
    const unsigned short* __restrict__ cb,   // [20096][128] bf16 centers, zero-padded
    const float* __restrict__ t,             // [8192]
    float* __restrict__ acc_slots)           // 4 x {sum,cnt} slots, 64B apart
{
    __shared__ __align__(16) char sB[4 * 2 * 4096];   // [wave][buf] 4KB tiles = 32 KB
    __shared__ float sWsum[4];
    __shared__ unsigned int sWcnt[4];

    const int tid  = threadIdx.x;
    const int lane = tid & 63;
    const int w    = tid >> 6;            // wave 0..3
    const int chunk   = blockIdx.x;       // 0..31, tiles chunk + 32*j
    const int rowbase = blockIdx.y * 256; // feature row block
    const int nt = (NTILES16 - 1 - chunk) / NCHUNK + 1;  // 40 (chunk<8) else 39

    const int wf = w * 64;                // wave feature offset (4 groups of 64)
    const int l15 = lane & 15;
    const int kg  = lane >> 4;

    // ---- feature fragments + t values -> registers (wave-lifetime) ----
    bf16x8 ffr[4][4];                     // [ks][ff]
    float tvr[4];
    #pragma unroll
    for (int ff = 0; ff < 4; ++ff) {
        const int m = rowbase + wf + ff * 16 + l15;
        const unsigned short* src = fb + (size_t)m * D_N + kg * 8;
        #pragma unroll
        for (int ks = 0; ks < 4; ++ks)
            ffr[ks][ff] = *(const bf16x8*)(src + ks * 32);
        tvr[ff] = t[m];
    }

    // ---- wave-private center staging: 16-row tile = 4KB = 4 global_load_lds.
    // Linear LDS dest + involution-swizzled global source (proven R8 pattern).
    auto STAGE = [&](int buf, int tile) {
        const char* g = (const char*)cb + (size_t)tile * 4096;
        #pragma unroll
        for (int i = 0; i < 4; ++i) {
            const int loff = w * 8192 + buf * 4096 + i * 1024;   // wave-uniform
            const int x = i * 1024 + lane * 16;                  // within tile
            const int sx = x ^ (((x >> 8) & 7) << 4);            // involution
            __builtin_amdgcn_global_load_lds((GUint*)(g + sx),
                (LUint*)(sB + loff), 16, 0, 0);
        }
    };

    STAGE(0, chunk);
    if (nt > 1) STAGE(1, chunk + NCHUNK);

    float ls0 = 0.0f, ls1 = 0.0f;
    unsigned int wcnt = 0;

    for (int j = 0; j < nt; ++j) {
        // per-wave pacing: tile j landed when <=4 loads (tile j+1) outstanding
        if (j + 1 < nt) { asm volatile("s_waitcnt vmcnt(4)" ::: "memory"); }
        else            { asm volatile("s_waitcnt vmcnt(0)" ::: "memory"); }

        // pull the whole 4KB tile into cfr regs (4 x ds_read_b128)
        const char* sbase = sB + w * 8192 + (j & 1) * 4096;
        bf16x8 cfr[4];
        #pragma unroll
        for (int ks = 0; ks < 4; ++ks) {
            int p = l15 * 256 + ks * 64 + kg * 16;
            p ^= ((l15 & 7) << 4);
            cfr[ks] = *(const bf16x8*)(sbase + p);
        }
        // buffer dead once cfr is in regs: fence, then refill it for tile j+2
        asm volatile("s_waitcnt lgkmcnt(0)" ::: "memory");
        __builtin_amdgcn_sched_barrier(0);
        if (j + 2 < nt) STAGE(j & 1, chunk + (j + 2) * NCHUNK);

        f32x4 acc[4];                     // [ff]
        #pragma unroll
        for (int ff = 0; ff < 4; ++ff)
            #pragma unroll
            for (int r = 0; r < 4; ++r)
                acc[ff][r] = tvr[ff];

        #pragma unroll
        for (int ks = 0; ks < 4; ++ks)
            #pragma unroll
            for (int ff = 0; ff < 4; ++ff)
                acc[ff] = __builtin_amdgcn_mfma_f32_16x16x32_bf16(
                    cfr[ks], ffr[ks][ff], acc[ff], 0, 0, 0);

        // epilogue: loss already in acc; fmax+add + v_cmp (count stays SALU)
        #pragma unroll
        for (int ff = 0; ff < 4; ++ff)
            #pragma unroll
            for (int r = 0; r < 4; ++r) {
                const float l = acc[ff][r];
                if (ff & 1) ls1 += fmaxf(l, 0.0f); else ls0 += fmaxf(l, 0.0f);
                wcnt += (unsigned int)__popcll(__ballot(l > 0.0f));
            }
    }

    float lsum = ls0 + ls1;
    #pragma unroll
    for (int off = 32; off; off >>= 1) lsum += __shfl_xor(lsum, off);
    if (lane == 0) { sWsum[w] = lsum; sWcnt[w] = wcnt; }
    __syncthreads();
    if (tid == 0) {
        float s = 0.0f; unsigned int c = 0;
        #pragma unroll
        for (int i = 0; i < 4; ++i) { s += sWsum[i]; c += sWcnt[i]; }
        const int slot = (blockIdx.x ^ blockIdx.y) & 3;        // spread atomics
        atomicAdd(acc_slots + slot * 16, s);
        atomicAdd((unsigned int*)(acc_slots + slot * 16 + 1), c);
    }
}

// ---- kernel 3: reduce corrections + slots, finalize ----
__global__ __launch_bounds__(256) void k_finalize(
    const float* __restrict__ acc_slots,
    const float* __restrict__ corr_s, const unsigned int* __restrict__ corr_c,
    float* __restrict__ out)
{
    __shared__ float ss[4];
    __shared__ unsigned int sc[4];
    const int tid = threadIdx.x;
    const int lane = tid & 63;
    const int w = tid >> 6;
    float cs = 0.0f; unsigned int cc = 0;
    for (int i = tid; i < B_N; i += 256) { cs += corr_s[i]; cc += corr_c[i]; }
    #pragma unroll
    for (int off = 32; off; off >>= 1) {
        cs += __shfl_xor(cs, off);
        cc += __shfl_xor(cc, off);
    }
    if (lane == 0) { ss[w] = cs; sc[w] = cc; }
    __syncthreads();
    if (tid == 0) {
        float S = -(ss[0] + ss[1] + ss[2] + ss[3]);
        long long C = -(long long)(sc[0] + sc[1] + sc[2] + sc[3]);
        #pragma unroll
        for (int i = 0; i < 4; ++i) {
            S += acc_slots[i * 16];
            C += (long long)((const unsigned int*)acc_slots)[i * 16 + 1];
        }
        out[0] = (C > 0) ? (S / (float)C) : 0.0f;
    }
}

extern "C" void kernel_launch(void* const* d_in, const int* in_sizes, int n_in,
                              void* d_out, int out_size, void* d_ws, size_t ws_size,
                              hipStream_t stream) {
    const float* feat    = (const float*)d_in[0];
    const float* centers = (const float*)d_in[1];
    const int*   labels  = (const int*)d_in[2];
    float* out = (float*)d_out;

    char* ws = (char*)d_ws;
    float*          acc_slots = (float*)ws;                          // 256 B (4 x 64B)
    float*          t         = (float*)(ws + 1024);                 // 32 KB
    float*          corr_s    = (float*)(ws + 65536);                // 32 KB
    unsigned int*   corr_c    = (unsigned int*)(ws + 98304);         // 32 KB
    unsigned short* fb        = (unsigned short*)(ws + 131072);      // 2 MB
    unsigned short* cb        = (unsigned short*)(ws + 4*1024*1024); // 5.14 MB

    hipMemsetAsync(ws, 0, 256, stream);
    k_prep<<<NORM_BLOCKS + CONV_BLOCKS, 256, 0, stream>>>(
        feat, centers, labels, fb, cb, t, corr_s, corr_c);
    dim3 grid(NCHUNK, 32);
    k_main<<<grid, 256, 0, stream>>>(fb, cb, t, acc_slots);
    k_finalize<<<1, 256, 0, stream>>>(acc_slots, corr_s, corr_c, out);
}

// Round 11
// 76.892 us; speedup vs baseline: 1.0020x; 1.0020x over previous
//
#include <hip/hip_runtime.h>

#define B_N 8192
#define C_N 20000
#define D_N 128
#define CPAD 20096              // 628 * 32
#define NPAD 96
#define NTILES32 628            // 32-row center tiles
#define NCHUNK 24               // tiles strided: tile = chunk + 24*j ; 24*32=768 blocks = 3/CU
#define MARGIN_F 0.15001125f    // 0.15 + (1/40000)*(0.6-0.15)

#define NORM_BLOCKS 1024        // 8 rows per block (4 waves x 2 rows)
#define CONV_BLOCKS 2512        // CPAD*128/4/256

typedef __attribute__((ext_vector_type(8))) short bf16x8;
typedef __attribute__((ext_vector_type(4))) float f32x4;

typedef __attribute__((address_space(1))) const unsigned int GUint;
typedef __attribute__((address_space(3))) unsigned int LUint;

__device__ __forceinline__ unsigned short f2bf(float x) {
    union { float f; unsigned int u; } v; v.f = x;
    unsigned int r = v.u + 0x7fffu + ((v.u >> 16) & 1u);
    return (unsigned short)(r >> 16);
}
__device__ __forceinline__ float bf2f(unsigned short h) {
    union { unsigned int u; float f; } v; v.u = ((unsigned int)h) << 16; return v.f;
}

// ---- kernel 1 (fused prep): blocks [0,1024) normalize features (float4, 2
// rows/wave); rest convert centers -> bf16 (zero-padded). Per-row corrections
// for the max-identity accounting:
//   S_valid = M + CPAD*sum(t) - sum_f[relu(t+pb)] - NPAD*sum_f[relu(t)]
//   C_valid = C_all - sum_f[1(t+pb>0)] - NPAD*sum_f[1(t>0)]
__global__ __launch_bounds__(256) void k_prep(
    const float* __restrict__ feat, const float* __restrict__ centers,
    const int* __restrict__ labels, unsigned short* __restrict__ fb,
    unsigned short* __restrict__ cb, float* __restrict__ t,
    float* __restrict__ corr_s, unsigned int* __restrict__ corr_c)
{
    const int bid = blockIdx.x;
    if (bid < NORM_BLOCKS) {
        const int lane = threadIdx.x & 63;
        const int l32  = lane & 31;
        const int row  = bid * 8 + ((threadIdx.x >> 6) << 1) + (lane >> 5);
        const float4 fv = *(const float4*)(feat + (size_t)row * D_N + l32 * 4);
        float ss = fv.x * fv.x + fv.y * fv.y + fv.z * fv.z + fv.w * fv.w;
        #pragma unroll
        for (int off = 16; off; off >>= 1) ss += __shfl_xor(ss, off);
        const float scale = 1.0f / fmaxf(sqrtf(ss), 1e-12f);
        const float a0 = fv.x * scale, a1 = fv.y * scale;
        const float a2 = fv.z * scale, a3 = fv.w * scale;
        ushort4 o; o.x = f2bf(a0); o.y = f2bf(a1); o.z = f2bf(a2); o.w = f2bf(a3);
        *(ushort4*)(fb + (size_t)row * D_N + l32 * 4) = o;

        const int lab = labels[row];
        const float4 cv = *(const float4*)(centers + (size_t)lab * D_N + l32 * 4);
        float pd = a0 * cv.x + a1 * cv.y + a2 * cv.z + a3 * cv.w;       // fp32 dot
        float pb = bf2f(o.x) * bf2f(f2bf(cv.x)) + bf2f(o.y) * bf2f(f2bf(cv.y))
                 + bf2f(o.z) * bf2f(f2bf(cv.z)) + bf2f(o.w) * bf2f(f2bf(cv.w));
        #pragma unroll
        for (int off = 16; off; off >>= 1) {
            pd += __shfl_xor(pd, off);
            pb += __shfl_xor(pb, off);
        }
        if (l32 == 0) {
            const float tb = MARGIN_F - pd;
            t[row] = tb;
            corr_s[row] = fmaxf(tb + pb, 0.0f) + (float)NPAD * fmaxf(tb, 0.0f);
            corr_c[row] = ((tb + pb > 0.0f) ? 1u : 0u) + ((tb > 0.0f) ? (unsigned)NPAD : 0u);
        }
    } else {
        const int idx = (bid - NORM_BLOCKS) * 256 + threadIdx.x;
        const int e = idx * 4;
        const int row = e >> 7;
        ushort4 o;
        if (row < C_N) {
            const float4 v = *(const float4*)(centers + e);
            o.x = f2bf(v.x); o.y = f2bf(v.y); o.z = f2bf(v.z); o.w = f2bf(v.w);
        } else {
            o.x = 0; o.y = 0; o.z = 0; o.w = 0;
        }
        *(ushort4*)(cb + e) = o;
    }
}

// ---- kernel 2: main. R8 structure (proven: 64f x 32c wave tile, 4-wave block,
// (256,3) no-spill, 2-phase LDS dbuf) with the VALU diet:
//   - acc zero-init via MFMA C-operand (zero4) at ks=0  -> init movs gone
//   - max-identity: accumulate M = sum max(d, -t); no per-element +t
//   - epilogue exactly 3 VALU/elem: v_max, v_add, v_cmp (+SALU popcount)
__global__ __launch_bounds__(256, 3) void k_main(
    const unsigned short* __restrict__ fb,   // [8192][128] bf16 normalized features
    const unsigned short* __restrict__ cb,   // [20096][128] bf16 centers, zero-padded
    const float* __restrict__ t,             // [8192]
    float* __restrict__ acc_slots)           // 4 x {M, cnt} slots, 64B apart
{
    __shared__ __align__(16) unsigned short sB[2][32 * 128];   // 2 x 8 KB
    __shared__ float sWsum[4];
    __shared__ unsigned int sWcnt[4];

    const int tid  = threadIdx.x;
    const int lane = tid & 63;
    const int w    = tid >> 6;            // wave 0..3
    const int chunk   = blockIdx.x;       // 0..23, tiles chunk + 24*j
    const int rowbase = blockIdx.y * 256; // feature row block
    const int nt = (NTILES32 - 1 - chunk) / NCHUNK + 1;  // 27 (chunk<4) else 26

    const int wf = w * 64;                // wave feature offset
    const int l15 = lane & 15;
    const int kg  = lane >> 4;

    // ---- feature fragments + NEGATED t -> registers (block-lifetime) ----
    bf16x8 ffr[4][4];                     // [ks][ff]
    float ntv[4];
    #pragma unroll
    for (int ff = 0; ff < 4; ++ff) {
        const int m = rowbase + wf + ff * 16 + l15;
        const unsigned short* src = fb + (size_t)m * D_N + kg * 8;
        #pragma unroll
        for (int ks = 0; ks < 4; ++ks)
            ffr[ks][ff] = *(const bf16x8*)(src + ks * 32);
        ntv[ff] = -t[m];
    }

    const f32x4 zero4 = {0.0f, 0.0f, 0.0f, 0.0f};   // pinned C-operand

    // ---- center staging: linear LDS dest + involution-swizzled global source ----
    const char* gB0 = (const char*)cb;
    auto STAGE = [&](int buf, int tile) {
        const char* gB = gB0 + (size_t)tile * 8192;
        #pragma unroll
        for (int i = 0; i < 2; ++i) {
            const int loff = w * 1024 + i * 4096;          // wave-uniform LDS base
            const int x = loff + lane * 16;
            const int sx = x ^ (((x >> 8) & 7) << 4);      // involution
            __builtin_amdgcn_global_load_lds((GUint*)(gB + sx),
                (LUint*)((char*)sB[buf] + loff), 16, 0, 0);
        }
    };

    STAGE(0, chunk);
    __syncthreads();

    float ls[4] = {0.0f, 0.0f, 0.0f, 0.0f};
    unsigned int wcnt = 0;

    for (int j = 0; j < nt; ++j) {
        const int cur = j & 1;
        if (j + 1 < nt) STAGE(cur ^ 1, chunk + (j + 1) * NCHUNK);  // prefetch first

        const char* sbase = (const char*)sB[cur];
        f32x4 acc[2][4];                  // [fc][ff] raw dots
        #pragma unroll
        for (int ks = 0; ks < 4; ++ks) {
            bf16x8 cfr[2];
            #pragma unroll
            for (int fc = 0; fc < 2; ++fc) {
                const int row = fc * 16 + l15;                 // center row in tile
                int p = row * 256 + ks * 64 + kg * 16;
                p ^= ((row & 7) << 4);
                cfr[fc] = *(const bf16x8*)(sbase + p);
            }
            if (ks == 0) {
                #pragma unroll
                for (int fc = 0; fc < 2; ++fc)
                    #pragma unroll
                    for (int ff = 0; ff < 4; ++ff)
                        acc[fc][ff] = __builtin_amdgcn_mfma_f32_16x16x32_bf16(
                            cfr[fc], ffr[0][ff], zero4, 0, 0, 0);   // overwrite-init
            } else {
                #pragma unroll
                for (int fc = 0; fc < 2; ++fc)
                    #pragma unroll
                    for (int ff = 0; ff < 4; ++ff)
                        acc[fc][ff] = __builtin_amdgcn_mfma_f32_16x16x32_bf16(
                            cfr[fc], ffr[ks][ff], acc[fc][ff], 0, 0, 0);
            }
        }

        // epilogue: 3 VALU/elem (v_max, v_add, v_cmp) + SALU ballot-count
        #pragma unroll
        for (int fc = 0; fc < 2; ++fc)
            #pragma unroll
            for (int ff = 0; ff < 4; ++ff)
                #pragma unroll
                for (int r = 0; r < 4; ++r) {
                    const float d = acc[fc][ff][r];
                    ls[fc * 2 + (ff & 1)] += fmaxf(d, ntv[ff]);
                    wcnt += (unsigned int)__popcll(__ballot(d > ntv[ff]));
                }

        __syncthreads();   // drains prefetch vmcnt; read buffer freed
    }

    float lsum = (ls[0] + ls[1]) + (ls[2] + ls[3]);
    #pragma unroll
    for (int off = 32; off; off >>= 1) lsum += __shfl_xor(lsum, off);
    if (lane == 0) { sWsum[w] = lsum; sWcnt[w] = wcnt; }
    __syncthreads();
    if (tid == 0) {
        float s = 0.0f; unsigned int c = 0;
        #pragma unroll
        for (int i = 0; i < 4; ++i) { s += sWsum[i]; c += sWcnt[i]; }
        const int slot = (blockIdx.x ^ blockIdx.y) & 3;        // spread atomics
        atomicAdd(acc_slots + slot * 16, s);
        atomicAdd((unsigned int*)(acc_slots + slot * 16 + 1), c);
    }
}

// ---- kernel 3: reduce corrections + t-sum + slots, finalize in double ----
__global__ __launch_bounds__(256) void k_finalize(
    const float* __restrict__ acc_slots, const float* __restrict__ t,
    const float* __restrict__ corr_s, const unsigned int* __restrict__ corr_c,
    float* __restrict__ out)
{
    __shared__ float ss[4], st[4];
    __shared__ unsigned int sc[4];
    const int tid = threadIdx.x;
    const int lane = tid & 63;
    const int w = tid >> 6;
    float cs = 0.0f, ct = 0.0f; unsigned int cc = 0;
    for (int i = tid; i < B_N; i += 256) {
        cs += corr_s[i]; ct += t[i]; cc += corr_c[i];
    }
    #pragma unroll
    for (int off = 32; off; off >>= 1) {
        cs += __shfl_xor(cs, off);
        ct += __shfl_xor(ct, off);
        cc += __shfl_xor(cc, off);
    }
    if (lane == 0) { ss[w] = cs; st[w] = ct; sc[w] = cc; }
    __syncthreads();
    if (tid == 0) {
        const double CS = (double)ss[0] + ss[1] + ss[2] + ss[3];
        const double CT = (double)st[0] + st[1] + st[2] + st[3];
        const long long CC = (long long)sc[0] + sc[1] + sc[2] + sc[3];
        double M = 0.0; long long Call = 0;
        #pragma unroll
        for (int i = 0; i < 4; ++i) {
            M += (double)acc_slots[i * 16];
            Call += (long long)((const unsigned int*)acc_slots)[i * 16 + 1];
        }
        const double S = M + (double)CPAD * CT - CS;
        const long long C = Call - CC;
        out[0] = (C > 0) ? (float)(S / (double)C) : 0.0f;
    }
}

extern "C" void kernel_launch(void* const* d_in, const int* in_sizes, int n_in,
                              void* d_out, int out_size, void* d_ws, size_t ws_size,
                              hipStream_t stream) {
    const float* feat    = (const float*)d_in[0];
    const float* centers = (const float*)d_in[1];
    const int*   labels  = (const int*)d_in[2];
    float* out = (float*)d_out;

    char* ws = (char*)d_ws;
    float*          acc_slots = (float*)ws;                          // 256 B (4 x 64B)
    float*          t         = (float*)(ws + 1024);                 // 32 KB
    float*          corr_s    = (float*)(ws + 65536);                // 32 KB
    unsigned int*   corr_c    = (unsigned int*)(ws + 98304);         // 32 KB
    unsigned short* fb        = (unsigned short*)(ws + 131072);      // 2 MB
    unsigned short* cb        = (unsigned short*)(ws + 4*1024*1024); // 5.14 MB

    hipMemsetAsync(ws, 0, 256, stream);
    k_prep<<<NORM_BLOCKS + CONV_BLOCKS, 256, 0, stream>>>(
        feat, centers, labels, fb, cb, t, corr_s, corr_c);
    dim3 grid(NCHUNK, 32);
    k_main<<<grid, 256, 0, stream>>>(fb, cb, t, acc_slots);
    k_finalize<<<1, 256, 0, stream>>>(acc_slots, t, corr_s, corr_c, out);
}